// Round 14
// baseline (195.912 us; speedup 1.0000x reference)
//
#include <hip/hip_runtime.h>
#include <hip/hip_bf16.h>
#include <math.h>

// HarmonicCausalSelfAttention: B=4 T=2048 C=1024 H=16 R=64 D=64, alpha=0.7
// R13 pipeline (4 launches):
//   k_prep : weights -> fragment-linear bf16 hi/lo (unchanged)
//   k_qkv  : fused x->(t)->q,k,v (unchanged)
//   k_attn : causal flash attn; R13: un-paired 128-row blocks -> grid 1024,
//            LDS 40KB, launch_bounds(256,4) => 4 blocks/CU = 4 waves/SIMD
//            (R10-12 evidence: instruction-stream/TLP-bound). Heavy-first
//            dispatch per XCD chunk for causal balance. Shared K/V frag reads
//            across 2 q-frags, fixed-shift softmax, gll16 staging.
//   k_cout : fused y->(ty)->out (unchanged)

#define NB 4
#define NT 2048
#define NC 1024
#define NH 16
#define NR 64
#define ND 64
#define NM (NB * NT)  // 8192

typedef __attribute__((ext_vector_type(8))) short short8;
typedef __attribute__((ext_vector_type(4))) short short4v;
typedef __attribute__((ext_vector_type(4))) float f32x4;
typedef __attribute__((ext_vector_type(4))) float float4v;
typedef __attribute__((ext_vector_type(4))) int int4v;

__device__ __forceinline__ short f2bf(float f) {
    union { __hip_bfloat16 h; short s; } u;
    u.h = __float2bfloat16(f);
    return u.s;
}
__device__ __forceinline__ float bf2f(short s) {
    union { short s; __hip_bfloat16 h; } u;
    u.s = s;
    return __bfloat162float(u.h);
}
__device__ __forceinline__ f32x4 MFMA(short8 a, short8 b, f32x4 c) {
    return __builtin_amdgcn_mfma_f32_16x16x32_bf16(a, b, c, 0, 0, 0);
}
__device__ __forceinline__ float exp2_(float x) {
#if __has_builtin(__builtin_amdgcn_exp2f)
    return __builtin_amdgcn_exp2f(x);
#else
    return exp2f(x);
#endif
}

// async global->LDS, 16B per lane (LDS dest = wave-uniform base + lane*16)
typedef const __attribute__((address_space(1))) unsigned int* gas_ptr;
typedef __attribute__((address_space(3))) unsigned int* las_ptr;
__device__ __forceinline__ void gll16(const void* g, void* l) {
    __builtin_amdgcn_global_load_lds((gas_ptr)g, (las_ptr)l, 16, 0, 0);
}

// ---- weight prep -> fragment-linear layout (unchanged from R10-R12).
__global__ __launch_bounds__(256) void k_prep(const float* __restrict__ qV, const float* __restrict__ kV,
                                              const float* __restrict__ vV, const float* __restrict__ cV,
                                              const float* __restrict__ qU, const float* __restrict__ kU,
                                              const float* __restrict__ vU, const float* __restrict__ cU,
                                              short* __restrict__ Whi, short* __restrict__ Wlo) {
    const int idx = blockIdx.x * 256 + threadIdx.x;  // 0..65535
    const int mat = idx >> 13;                       // 8 mats x 8192 fragments
    const int f = idx & 8191;
    const int l = f & 63;
    const int rest = f >> 6;  // 0..127
    const float* src;
    switch (mat) {
        case 0: src = qV; break;
        case 1: src = kV; break;
        case 2: src = vV; break;
        case 3: src = cV; break;
        case 4: src = qU; break;
        case 5: src = kU; break;
        case 6: src = vU; break;
        default: src = cU; break;
    }
    int row, col, stride;
    if (mat < 4) {
        const int s = rest & 31, nt = rest >> 5;
        row = nt * 16 + (l & 15);
        col = s * 32 + (l >> 4) * 8;
        stride = NC;
    } else {
        const int ks = rest & 1, tn = rest >> 1;
        row = tn * 16 + (l & 15);
        col = ks * 32 + (l >> 4) * 8;
        stride = NR;
    }
    float sc = 1.0f;
    if (mat < 4) sc = powf((float)(row + 1), -0.7f);
    if (mat == 4) sc = 0.125f * 1.44269504088896f;  // fold scale and log2(e)
    const float* p = src + (size_t)row * stride + col;
    const float4v a = *(const float4v*)p;
    const float4v b = *(const float4v*)(p + 4);
    float v[8] = {a[0], a[1], a[2], a[3], b[0], b[1], b[2], b[3]};
    short* oh = Whi + (size_t)mat * 65536 + (size_t)f * 8;
    short* ol = Wlo + (size_t)mat * 65536 + (size_t)f * 8;
    short4v h0, h1, l0, l1;
#pragma unroll
    for (int j = 0; j < 8; j++) {
        const float fv = v[j] * sc;
        const short h = f2bf(fv);
        const short lo = f2bf(fv - bf2f(h));
        if (j < 4) { h0[j] = h; l0[j] = lo; } else { h1[j - 4] = h; l1[j - 4] = lo; }
    }
    *(short4v*)oh = h0;
    *(short4v*)(oh + 4) = h1;
    *(short4v*)ol = l0;
    *(short4v*)(ol + 4) = l1;
}

// ---- fused q/k/v (unchanged from R10-R12): 256 blocks x 32 m-rows, 8 waves.
__global__ __launch_bounds__(512, 2) void k_qkv(const float* __restrict__ X,
                                                const short* __restrict__ Whi, const short* __restrict__ Wlo,
                                                short* __restrict__ qb, short* __restrict__ kb,
                                                short* __restrict__ vtb) {
    __shared__ __align__(16) char Xl[2][16384];  // 32 rows x 128 f32, swizzled, dbuf
    __shared__ __align__(16) short Thi[32 * 200];
    __shared__ __align__(16) short Tlov[32 * 72];
    const int tid = threadIdx.x;
    const int w = tid >> 6, l = tid & 63;
    const int lr = l & 15, lk = l >> 4;
    const int g = w & 3, mg = w >> 2;
    const int mb = blockIdx.x * 32;

    auto stageX = [&](int buf, int win) {
#pragma unroll
        for (int q = 0; q < 2; q++) {
            const int r = q * 16 + w * 2 + (l >> 5);
            const int c = l & 31;
            const int sc16 = c ^ (r & 15);
            const float* gp = X + (size_t)(mb + r) * NC + win * 128 + sc16 * 4;
            gll16(gp, (char*)Xl[buf] + q * 8192 + w * 1024);
        }
    };

    const short* Wqk_f = (g < 2) ? Whi : (Whi + 65536);
    const int tA = ((g & 1) * 2) * 32;
    const int tB = tA + 32;
    const int tV = g * 32;
    const short* vfh = Whi + 2 * 65536;
    const short* vfl = Wlo + 2 * 65536;

    f32x4 a0 = 0.0f, a1 = 0.0f, av = 0.0f;
    const int xrow = (mg * 16 + lr) * 512;
    stageX(0, 0);
    for (int win = 0; win < 8; ++win) {
        const int buf = win & 1;
        __syncthreads();
        if (win < 7) stageX(buf ^ 1, win + 1);
        const char* XB = Xl[buf];
#pragma unroll
        for (int kk = 0; kk < 4; ++kk) {
            const int cb = kk * 8 + lk * 2;
            const float4v xa = *(const float4v*)(XB + xrow + ((cb ^ lr) << 4));
            const float4v xb = *(const float4v*)(XB + xrow + (((cb + 1) ^ lr) << 4));
            float xv[8] = {xa[0], xa[1], xa[2], xa[3], xb[0], xb[1], xb[2], xb[3]};
            short8 xh, xl8;
#pragma unroll
            for (int jj = 0; jj < 8; jj++) {
                const short h = f2bf(xv[jj]);
                xh[jj] = h;
                xl8[jj] = f2bf(xv[jj] - bf2f(h));
            }
            const int s = win * 4 + kk;
            const short8 wa = *(const short8*)(Wqk_f + (size_t)((tA + s) * 64 + l) * 8);
            const short8 wb = *(const short8*)(Wqk_f + (size_t)((tB + s) * 64 + l) * 8);
            const short8 wvh = *(const short8*)(vfh + (size_t)((tV + s) * 64 + l) * 8);
            const short8 wvl = *(const short8*)(vfl + (size_t)((tV + s) * 64 + l) * 8);
            a0 = MFMA(xh, wa, a0);
            a1 = MFMA(xh, wb, a1);
            av = MFMA(xh, wvh, av);
            av = MFMA(xh, wvl, av);
            av = MFMA(xl8, wvh, av);
        }
    }
    {
        const int p = g >> 1;
        const int colA = p * 64 + (g & 1) * 32 + lr;
        const int colB = colA + 16;
        const int colV = 128 + g * 16 + lr;
#pragma unroll
        for (int i = 0; i < 4; i++) {
            const int row = mg * 16 + lk * 4 + i;
            Thi[row * 200 + colA] = f2bf(a0[i]);
            Thi[row * 200 + colB] = f2bf(a1[i]);
            const short hv = f2bf(av[i]);
            Thi[row * 200 + colV] = hv;
            Tlov[row * 72 + g * 16 + lr] = f2bf(av[i] - bf2f(hv));
        }
    }
    __syncthreads();
    const short* qUf = Whi + 4 * 65536;
    const short* kUf = Whi + 5 * 65536;
    const short* vUfh = Whi + 6 * 65536;
    const short* vUfl = Wlo + 6 * 65536;
    short8 tf[2][3][2];
    short8 tfl[2][2];
#pragma unroll
    for (int m2 = 0; m2 < 2; m2++) {
        const int trow = m2 * 16 + lr;
#pragma unroll
        for (int ks = 0; ks < 2; ks++) {
#pragma unroll
            for (int p = 0; p < 3; p++)
                tf[m2][p][ks] = *(const short8*)(Thi + trow * 200 + p * 64 + ks * 32 + lk * 8);
            tfl[m2][ks] = *(const short8*)(Tlov + trow * 72 + ks * 32 + lk * 8);
        }
    }
    const int bb = mb >> 11, mt = mb & (NT - 1);
#pragma unroll 2
    for (int nt = 0; nt < 8; nt++) {
        const int tn = w * 8 + nt;
        short8 uq[2], uk[2], uvh[2], uvl[2];
#pragma unroll
        for (int ks = 0; ks < 2; ks++) {
            const size_t off2 = (size_t)((tn * 2 + ks) * 64 + l) * 8;
            uq[ks] = *(const short8*)(qUf + off2);
            uk[ks] = *(const short8*)(kUf + off2);
            uvh[ks] = *(const short8*)(vUfh + off2);
            uvl[ks] = *(const short8*)(vUfl + off2);
        }
#pragma unroll
        for (int m2 = 0; m2 < 2; m2++) {
            f32x4 aq = 0.0f, ak = 0.0f, avv = 0.0f;
#pragma unroll
            for (int ks = 0; ks < 2; ks++) {
                aq = MFMA(uq[ks], tf[m2][0][ks], aq);
                ak = MFMA(uk[ks], tf[m2][1][ks], ak);
                avv = MFMA(tf[m2][2][ks], uvh[ks], avv);
                avv = MFMA(tf[m2][2][ks], uvl[ks], avv);
                avv = MFMA(tfl[m2][ks], uvh[ks], avv);
            }
            const int tt = mt + m2 * 16 + lr;
            const int nq = tn * 16 + lk * 4;
            const int hhq = nq >> 6, ddq = nq & 63;
            short4v pq, pk;
#pragma unroll
            for (int i = 0; i < 4; i++) { pq[i] = f2bf(aq[i]); pk[i] = f2bf(ak[i]); }
            *(short4v*)(qb + ((size_t)(bb * NH + hhq) * NT + tt) * ND + ddq) = pq;
            *(short4v*)(kb + ((size_t)(bb * NH + hhq) * NT + tt) * ND + ddq) = pk;
            const int n = tn * 16 + lr;
            const int hhv = n >> 6, ddv = n & 63;
            const int tv = mt + m2 * 16 + lk * 4;
            short4v pv;
#pragma unroll
            for (int i = 0; i < 4; i++) pv[i] = f2bf(avv[i]);
            *(short4v*)(vtb + ((size_t)(bb * NH + hhv) * ND + ddv) * NT + tv) = pv;
        }
    }
}

// ---- fused c-path (unchanged from R10-R12): 256 blocks x 32 rows, 8 waves.
__global__ __launch_bounds__(512, 2) void k_cout(const short* __restrict__ Yb,
                                                 const short* __restrict__ Whi, const short* __restrict__ Wlo,
                                                 float* __restrict__ Out) {
    __shared__ __align__(16) char Yl[2][16384];
    __shared__ __align__(16) short tyhi[32 * 72];
    __shared__ __align__(16) short tylo[32 * 72];
    const int tid = threadIdx.x;
    const int w = tid >> 6, l = tid & 63;
    const int lr = l & 15, lk = l >> 4;
    const int g = w & 3, mg = w >> 2;
    const int mb = blockIdx.x * 32;
    const short* cVfh = Whi + 3 * 65536;
    const short* cVfl = Wlo + 3 * 65536;
    const short* cUfh = Whi + 7 * 65536;
    const short* cUfl = Wlo + 7 * 65536;

    auto stageY = [&](int buf, int win) {
#pragma unroll
        for (int q = 0; q < 2; q++) {
            const int r = q * 16 + w * 2 + (l >> 5);
            const int c = l & 31;
            const int sc16 = c ^ (r & 15);
            const short* gp = Yb + (size_t)(mb + r) * NC + win * 256 + sc16 * 8;
            gll16(gp, (char*)Yl[buf] + q * 8192 + w * 1024);
        }
    };

    const int tV = g * 32;
    f32x4 acc = 0.0f;
    const int xrow = (mg * 16 + lr) * 512;
    stageY(0, 0);
    for (int win = 0; win < 4; ++win) {
        const int buf = win & 1;
        __syncthreads();
        if (win < 3) stageY(buf ^ 1, win + 1);
        const char* YB = Yl[buf];
#pragma unroll
        for (int kk = 0; kk < 8; ++kk) {
            const short8 ah = *(const short8*)(YB + xrow + ((((kk * 4 + lk)) ^ lr) << 4));
            const int s = win * 8 + kk;
            const short8 wh = *(const short8*)(cVfh + (size_t)((tV + s) * 64 + l) * 8);
            const short8 wl = *(const short8*)(cVfl + (size_t)((tV + s) * 64 + l) * 8);
            acc = MFMA(ah, wh, acc);
            acc = MFMA(ah, wl, acc);
        }
    }
#pragma unroll
    for (int i = 0; i < 4; i++) {
        const int row = mg * 16 + lk * 4 + i;
        const short h = f2bf(acc[i]);
        tyhi[row * 72 + g * 16 + lr] = h;
        tylo[row * 72 + g * 16 + lr] = f2bf(acc[i] - bf2f(h));
    }
    __syncthreads();
    short8 th[2][2], tl[2][2];
#pragma unroll
    for (int m2 = 0; m2 < 2; m2++) {
        const int trow = m2 * 16 + lr;
#pragma unroll
        for (int ks = 0; ks < 2; ks++) {
            th[m2][ks] = *(const short8*)(tyhi + trow * 72 + ks * 32 + lk * 8);
            tl[m2][ks] = *(const short8*)(tylo + trow * 72 + ks * 32 + lk * 8);
        }
    }
#pragma unroll 2
    for (int nt = 0; nt < 8; nt++) {
        const int tn = w * 8 + nt;
        short8 uh[2], ul[2];
#pragma unroll
        for (int ks = 0; ks < 2; ks++) {
            const size_t off2 = (size_t)((tn * 2 + ks) * 64 + l) * 8;
            uh[ks] = *(const short8*)(cUfh + off2);
            ul[ks] = *(const short8*)(cUfl + off2);
        }
#pragma unroll
        for (int m2 = 0; m2 < 2; m2++) {
            f32x4 a = 0.0f;
#pragma unroll
            for (int ks = 0; ks < 2; ks++) {
                a = MFMA(uh[ks], th[m2][ks], a);
                a = MFMA(ul[ks], th[m2][ks], a);
                a = MFMA(uh[ks], tl[m2][ks], a);
            }
            const int mm = mb + m2 * 16 + lr;
            const int n = tn * 16 + lk * 4;
            *(float4v*)(Out + (size_t)mm * NC + n) = *(float4v*)&a;
        }
    }
}

// swizzled LDS fragment read: tile [64][64] bf16, row stride 128B, byte ^ (row&7)<<4
__device__ __forceinline__ short8 lds_frag(const short* base, int row, int cb) {
    return *(const short8*)((const char*)base + (((row << 7) + cb) ^ ((row & 7) << 4)));
}

// ---- causal flash attention R13: un-paired 128-row blocks, 4 blocks/CU.
// grid (16, B*H) = 1024 blocks; block j covers q rows [128j, 128j+128);
// wave w owns rows [128j+32w, +32) as 2 x 16-row frags. Heavy-first (j desc)
// within each XCD chunk. Fixed-shift softmax (P = 2^(S-16) via MFMA C-init).
__global__ __launch_bounds__(256, 4) void k_attn(const short* __restrict__ Qm,
                                                 const short* __restrict__ Km,
                                                 const short* __restrict__ Vt,
                                                 short* __restrict__ Y) {
    __shared__ __align__(16) short Kl[2][4096];  // [64][64] per buf, 16 KB
    __shared__ __align__(16) short Vl[2][4096];  // 16 KB
    __shared__ __align__(16) short Pl[4][1024];  // per-wave 16x64, frags sequential, 8 KB
    const int tid = threadIdx.x;
    const int w = tid >> 6, l = tid & 63;
    const int lr = l & 15, lk = l >> 4;
    // XCD chunking + heavy-first: XCD c = lin&7 owns bh [8c,8c+8); within each
    // bh, j descends with dispatch order (32-tile blocks launch first).
    const int lin = blockIdx.y * 16 + blockIdx.x;  // 1024 blocks
    const int nl = (lin & 7) * 128 + (lin >> 3);
    const int bh = nl >> 4;
    const int j = 15 - (nl & 15);
    const int np = 2 * j + 2;            // tiles staged by block
    const int diagw = 2 * j + (w >> 1);  // this wave's last (masked) tile
    const int q0 = 128 * j + 32 * w;

    const short* Kb = Km + (size_t)bh * NT * ND;
    const short* Vb = Vt + (size_t)bh * ND * NT;

    short8 qf[2][2];  // [frag][ks]
#pragma unroll
    for (int f = 0; f < 2; f++) {
#pragma unroll
        for (int ks = 0; ks < 2; ks++)
            qf[f][ks] = *(const short8*)(Qm + ((size_t)bh * NT + q0 + f * 16 + lr) * ND + ks * 32 + lk * 8);
    }

    // gll16 staging: LDS dest linear, global src pre-swizzled (rule #21)
    const int grow8 = w * 8 + (l >> 3);
    const int gcolb = (((l & 7) ^ ((l >> 3) & 7)) << 4);
    auto stage = [&](int buf, int kv0) {
        const char* kp = (const char*)Kb + (((size_t)(kv0 + grow8)) << 7) + gcolb;
        const char* vp = (const char*)Vb + (size_t)grow8 * (NT * 2) + kv0 * 2 + gcolb;
        char* kl = (char*)Kl[buf] + w * 1024;
        char* vl = (char*)Vl[buf] + w * 1024;
        gll16(kp, kl);
        gll16(kp + (32 << 7), kl + 4096);
        gll16(vp, vl);
        gll16(vp + (size_t)32 * NT * 2, vl + 4096);
    };

    f32x4 ls[2];
    f32x4 o[2][4];
#pragma unroll
    for (int f = 0; f < 2; f++) {
        ls[f] = 0.0f;
#pragma unroll
        for (int dt = 0; dt < 4; dt++) o[f][dt] = 0.0f;
    }

    char* plw = (char*)Pl[w];

    stage(0, 0);
    for (int it = 0; it < np; ++it) {
        const int buf = it & 1;
        __syncthreads();  // drains this tile's gll16 (vmcnt) + syncs
        if (it + 1 < np) stage(buf ^ 1, (it + 1) * 64);  // overlaps compute
        if (it > diagw) continue;  // wave done; still hits barrier each iter
        const short* KlB = Kl[buf];
        const short* VlB = Vl[buf];
        const bool diag = (it == diagw);
        // K fragments once, shared by both q-frags
        short8 kfr[2][4];
#pragma unroll
        for (int ks = 0; ks < 2; ks++)
#pragma unroll
            for (int nt = 0; nt < 4; nt++)
                kfr[ks][nt] = lds_frag(KlB, nt * 16 + lr, ks * 64 + lk * 16);
        // QK + softmax per frag (P buffer reused sequentially; in-order DS ops)
        short8 pb[2][2];
#pragma unroll
        for (int f = 0; f < 2; f++) {
            f32x4 sa[4];
#pragma unroll
            for (int nt = 0; nt < 4; nt++) sa[nt] = -16.0f;
            __builtin_amdgcn_s_setprio(1);
#pragma unroll
            for (int ks = 0; ks < 2; ks++)
#pragma unroll
                for (int nt = 0; nt < 4; nt++)
                    sa[nt] = MFMA(kfr[ks][nt], qf[f][ks], sa[nt]);
            __builtin_amdgcn_s_setprio(0);
            if (diag) {
                const int qrel = (w & 1) * 32 + f * 16 + lr;
#pragma unroll
                for (int nt = 0; nt < 4; nt++) {
                    const int kvb = nt * 16 + lk * 4;
#pragma unroll
                    for (int i = 0; i < 4; i++)
                        if (kvb + i > qrel) sa[nt][i] = -1e30f;
                }
            }
#pragma unroll
            for (int nt = 0; nt < 4; nt++) {
                f32x4 sv;
#pragma unroll
                for (int i = 0; i < 4; i++) sv[i] = exp2_(sa[nt][i]);
                ls[f] += sv;
                short4v pk;
#pragma unroll
                for (int i = 0; i < 4; i++) pk[i] = f2bf(sv[i]);
                *(short4v*)(plw + (((lr << 7) + ((nt * 16 + lk * 4) << 1)) ^ ((lr & 7) << 4))) = pk;
            }
            pb[f][0] = *(const short8*)(plw + (((lr << 7) + ((lk * 8) << 1)) ^ ((lr & 7) << 4)));
            pb[f][1] = *(const short8*)(plw + (((lr << 7) + ((32 + lk * 8) << 1)) ^ ((lr & 7) << 4)));
        }
        // V fragments once, shared by both q-frags
        short8 vfr[2][4];
#pragma unroll
        for (int ks = 0; ks < 2; ks++)
#pragma unroll
            for (int dt = 0; dt < 4; dt++)
                vfr[ks][dt] = lds_frag(VlB, dt * 16 + lr, ks * 64 + lk * 16);
        __builtin_amdgcn_s_setprio(1);
#pragma unroll
        for (int ks = 0; ks < 2; ks++)
#pragma unroll
            for (int dt = 0; dt < 4; dt++) {
                o[0][dt] = MFMA(vfr[ks][dt], pb[0][ks], o[0][dt]);
                o[1][dt] = MFMA(vfr[ks][dt], pb[1][ks], o[1][dt]);
            }
        __builtin_amdgcn_s_setprio(0);
    }

    const int b = bh >> 4, h = bh & 15;
#pragma unroll
    for (int f = 0; f < 2; f++) {
        float lsum = (ls[f][0] + ls[f][1]) + (ls[f][2] + ls[f][3]);
        lsum += __shfl_xor(lsum, 16);
        lsum += __shfl_xor(lsum, 32);
        const float inv = 1.0f / lsum;
        short* yp = Y + ((size_t)b * NT + (q0 + f * 16 + lr)) * NC + h * ND;
#pragma unroll
        for (int dt = 0; dt < 4; dt++) {
            short4v ya;
#pragma unroll
            for (int i = 0; i < 4; i++) ya[i] = f2bf(o[f][dt][i] * inv);
            *(short4v*)(yp + dt * 16 + lk * 4) = ya;
        }
    }
}

extern "C" void kernel_launch(void* const* d_in, const int* in_sizes, int n_in,
                              void* d_out, int out_size, void* d_ws, size_t ws_size,
                              hipStream_t stream) {
    const float* x = (const float*)d_in[0];
    const float* qU = (const float*)d_in[1];
    const float* qV = (const float*)d_in[2];
    const float* kU = (const float*)d_in[3];
    const float* kV = (const float*)d_in[4];
    const float* vU = (const float*)d_in[5];
    const float* vV = (const float*)d_in[6];
    const float* cU = (const float*)d_in[7];
    const float* cV = (const float*)d_in[8];
    float* out = (float*)d_out;

    char* ws = (char*)d_ws;
    size_t off = 0;
    auto take = [&](size_t bytes) {
        char* p = ws + off;
        off += (bytes + 255) & ~(size_t)255;
        return p;
    };
    short* Whi = (short*)take(8 * 65536 * 2);
    short* Wlo = (short*)take(8 * 65536 * 2);
    short* qb = (short*)take((size_t)NM * NC * 2);
    short* kb = (short*)take((size_t)NM * NC * 2);
    short* vtb = (short*)take((size_t)NM * NC * 2);
    short* yb = (short*)take((size_t)NM * NC * 2);

    k_prep<<<256, 256, 0, stream>>>(qV, kV, vV, cV, qU, kU, vU, cU, Whi, Wlo);
    k_qkv<<<256, 512, 0, stream>>>(x, Whi, Wlo, qb, kb, vtb);
    k_attn<<<dim3(16, NB * NH), 256, 0, stream>>>(qb, kb, vtb, yb);
    k_cout<<<256, 512, 0, stream>>>(yb, Whi, Wlo, out);
}

// Round 15
// 125.657 us; speedup vs baseline: 1.5591x; 1.5591x over previous
//
#include <hip/hip_runtime.h>
#include <hip/hip_bf16.h>
#include <math.h>

// HarmonicCausalSelfAttention: B=4 T=2048 C=1024 H=16 R=64 D=64, alpha=0.7
// R14 pipeline (4 launches):
//   k_prep : weights -> fragment-linear bf16 hi/lo (unchanged)
//   k_qkv  : fused x->(t)->q,k,v; R14: 512 blocks x 16 rows x 4 waves,
//            launch_bounds(256,4) -> 4 blocks/CU = 16 waves/CU (2x R10-13).
//   k_attn : REVERTED to R11 (best: 60.3us): A/B-paired 32-q-rows/wave,
//            shared K/V frag reads, single-tile dbuf staging, XCD swizzle,
//            fixed-shift softmax.
//   k_cout : fused y->(ty)->out; same 512x16x4 structure.

#define NB 4
#define NT 2048
#define NC 1024
#define NH 16
#define NR 64
#define ND 64
#define NM (NB * NT)  // 8192

typedef __attribute__((ext_vector_type(8))) short short8;
typedef __attribute__((ext_vector_type(4))) short short4v;
typedef __attribute__((ext_vector_type(4))) float f32x4;
typedef __attribute__((ext_vector_type(4))) float float4v;
typedef __attribute__((ext_vector_type(4))) int int4v;

__device__ __forceinline__ short f2bf(float f) {
    union { __hip_bfloat16 h; short s; } u;
    u.h = __float2bfloat16(f);
    return u.s;
}
__device__ __forceinline__ float bf2f(short s) {
    union { short s; __hip_bfloat16 h; } u;
    u.s = s;
    return __bfloat162float(u.h);
}
__device__ __forceinline__ f32x4 MFMA(short8 a, short8 b, f32x4 c) {
    return __builtin_amdgcn_mfma_f32_16x16x32_bf16(a, b, c, 0, 0, 0);
}
__device__ __forceinline__ float exp2_(float x) {
#if __has_builtin(__builtin_amdgcn_exp2f)
    return __builtin_amdgcn_exp2f(x);
#else
    return exp2f(x);
#endif
}

// async global->LDS, 16B per lane (LDS dest = wave-uniform base + lane*16)
typedef const __attribute__((address_space(1))) unsigned int* gas_ptr;
typedef __attribute__((address_space(3))) unsigned int* las_ptr;
__device__ __forceinline__ void gll16(const void* g, void* l) {
    __builtin_amdgcn_global_load_lds((gas_ptr)g, (las_ptr)l, 16, 0, 0);
}

// ---- weight prep -> fragment-linear layout (unchanged from R10-R13).
__global__ __launch_bounds__(256) void k_prep(const float* __restrict__ qV, const float* __restrict__ kV,
                                              const float* __restrict__ vV, const float* __restrict__ cV,
                                              const float* __restrict__ qU, const float* __restrict__ kU,
                                              const float* __restrict__ vU, const float* __restrict__ cU,
                                              short* __restrict__ Whi, short* __restrict__ Wlo) {
    const int idx = blockIdx.x * 256 + threadIdx.x;  // 0..65535
    const int mat = idx >> 13;                       // 8 mats x 8192 fragments
    const int f = idx & 8191;
    const int l = f & 63;
    const int rest = f >> 6;  // 0..127
    const float* src;
    switch (mat) {
        case 0: src = qV; break;
        case 1: src = kV; break;
        case 2: src = vV; break;
        case 3: src = cV; break;
        case 4: src = qU; break;
        case 5: src = kU; break;
        case 6: src = vU; break;
        default: src = cU; break;
    }
    int row, col, stride;
    if (mat < 4) {
        const int s = rest & 31, nt = rest >> 5;
        row = nt * 16 + (l & 15);
        col = s * 32 + (l >> 4) * 8;
        stride = NC;
    } else {
        const int ks = rest & 1, tn = rest >> 1;
        row = tn * 16 + (l & 15);
        col = ks * 32 + (l >> 4) * 8;
        stride = NR;
    }
    float sc = 1.0f;
    if (mat < 4) sc = powf((float)(row + 1), -0.7f);
    if (mat == 4) sc = 0.125f * 1.44269504088896f;  // fold scale and log2(e)
    const float* p = src + (size_t)row * stride + col;
    const float4v a = *(const float4v*)p;
    const float4v b = *(const float4v*)(p + 4);
    float v[8] = {a[0], a[1], a[2], a[3], b[0], b[1], b[2], b[3]};
    short* oh = Whi + (size_t)mat * 65536 + (size_t)f * 8;
    short* ol = Wlo + (size_t)mat * 65536 + (size_t)f * 8;
    short4v h0, h1, l0, l1;
#pragma unroll
    for (int j = 0; j < 8; j++) {
        const float fv = v[j] * sc;
        const short h = f2bf(fv);
        const short lo = f2bf(fv - bf2f(h));
        if (j < 4) { h0[j] = h; l0[j] = lo; } else { h1[j - 4] = h; l1[j - 4] = lo; }
    }
    *(short4v*)oh = h0;
    *(short4v*)(oh + 4) = h1;
    *(short4v*)ol = l0;
    *(short4v*)(ol + 4) = l1;
}

// ---- fused q/k/v: R14: 512 blocks x 16 m-rows, 256 threads (4 waves).
// Phase1: wave g -> {q-or-k tiles (g&1)*2,+1 (g<2: q, g>=2: k); v tile g}, FULL K.
// Phase2: in-register hi/lo -> Thi[16][200], Tlov[16][72].
// Phase3: wave w -> n-sixteenth (16 n-tiles).
__global__ __launch_bounds__(256, 4) void k_qkv(const float* __restrict__ X,
                                                const short* __restrict__ Whi, const short* __restrict__ Wlo,
                                                short* __restrict__ qb, short* __restrict__ kb,
                                                short* __restrict__ vtb) {
    __shared__ __align__(16) char Xl[2][8192];  // 16 rows x 128 f32, swizzled, dbuf
    __shared__ __align__(16) short Thi[16 * 200];
    __shared__ __align__(16) short Tlov[16 * 72];
    const int tid = threadIdx.x;
    const int w = tid >> 6, l = tid & 63;
    const int lr = l & 15, lk = l >> 4;
    const int g = w;
    const int mb = blockIdx.x * 16;

    // stage one 128-f32-col window (8 KB): 2 gll16/thread, coalesced.
    // LDS chunk (r, c) holds global 16B chunk (r, c ^ (r&15)).
    auto stageX = [&](int buf, int win) {
#pragma unroll
        for (int q = 0; q < 2; q++) {
            const int r = q * 8 + w * 2 + (l >> 5);
            const int c = l & 31;
            const int sc16 = c ^ (r & 15);
            const float* gp = X + (size_t)(mb + r) * NC + win * 128 + sc16 * 4;
            gll16(gp, (char*)Xl[buf] + q * 4096 + w * 1024);
        }
    };

    const short* Wqk_f = (g < 2) ? Whi : (Whi + 65536);
    const int tA = ((g & 1) * 2) * 32;
    const int tB = tA + 32;
    const int tV = g * 32;
    const short* vfh = Whi + 2 * 65536;
    const short* vfl = Wlo + 2 * 65536;

    f32x4 a0 = 0.0f, a1 = 0.0f, av = 0.0f;
    const int xrow = lr * 512;
    stageX(0, 0);
    for (int win = 0; win < 8; ++win) {
        const int buf = win & 1;
        __syncthreads();  // drains this window's gll16 + syncs buffers
        if (win < 7) stageX(buf ^ 1, win + 1);
        const char* XB = Xl[buf];
#pragma unroll
        for (int kk = 0; kk < 4; ++kk) {
            const int cb = kk * 8 + lk * 2;
            const float4v xa = *(const float4v*)(XB + xrow + ((cb ^ lr) << 4));
            const float4v xb = *(const float4v*)(XB + xrow + (((cb + 1) ^ lr) << 4));
            float xv[8] = {xa[0], xa[1], xa[2], xa[3], xb[0], xb[1], xb[2], xb[3]};
            short8 xh, xl8;
#pragma unroll
            for (int jj = 0; jj < 8; jj++) {
                const short h = f2bf(xv[jj]);
                xh[jj] = h;
                xl8[jj] = f2bf(xv[jj] - bf2f(h));
            }
            const int s = win * 4 + kk;
            const short8 wa = *(const short8*)(Wqk_f + (size_t)((tA + s) * 64 + l) * 8);
            const short8 wb = *(const short8*)(Wqk_f + (size_t)((tB + s) * 64 + l) * 8);
            const short8 wvh = *(const short8*)(vfh + (size_t)((tV + s) * 64 + l) * 8);
            const short8 wvl = *(const short8*)(vfl + (size_t)((tV + s) * 64 + l) * 8);
            a0 = MFMA(xh, wa, a0);
            a1 = MFMA(xh, wb, a1);
            av = MFMA(xh, wvh, av);
            av = MFMA(xh, wvl, av);
            av = MFMA(xl8, wvh, av);
        }
    }
    // ---- phase 2: own-acc convert -> Thi/Tlov
    {
        const int p = g >> 1;
        const int colA = p * 64 + (g & 1) * 32 + lr;
        const int colB = colA + 16;
        const int colV = 128 + g * 16 + lr;
#pragma unroll
        for (int i = 0; i < 4; i++) {
            const int row = lk * 4 + i;
            Thi[row * 200 + colA] = f2bf(a0[i]);
            Thi[row * 200 + colB] = f2bf(a1[i]);
            const short hv = f2bf(av[i]);
            Thi[row * 200 + colV] = hv;
            Tlov[row * 72 + g * 16 + lr] = f2bf(av[i] - bf2f(hv));
        }
    }
    __syncthreads();
    // ---- phase 3: this wave's 16 n-tiles
    const short* qUf = Whi + 4 * 65536;
    const short* kUf = Whi + 5 * 65536;
    const short* vUfh = Whi + 6 * 65536;
    const short* vUfl = Wlo + 6 * 65536;
    short8 tf[3][2];
    short8 tfl[2];
#pragma unroll
    for (int ks = 0; ks < 2; ks++) {
#pragma unroll
        for (int p = 0; p < 3; p++)
            tf[p][ks] = *(const short8*)(Thi + lr * 200 + p * 64 + ks * 32 + lk * 8);
        tfl[ks] = *(const short8*)(Tlov + lr * 72 + ks * 32 + lk * 8);
    }
    const int bb = mb >> 11, mt = mb & (NT - 1);
#pragma unroll 2
    for (int nt = 0; nt < 16; nt++) {
        const int tn = w * 16 + nt;
        short8 uq[2], uk[2], uvh[2], uvl[2];
#pragma unroll
        for (int ks = 0; ks < 2; ks++) {
            const size_t off2 = (size_t)((tn * 2 + ks) * 64 + l) * 8;
            uq[ks] = *(const short8*)(qUf + off2);
            uk[ks] = *(const short8*)(kUf + off2);
            uvh[ks] = *(const short8*)(vUfh + off2);
            uvl[ks] = *(const short8*)(vUfl + off2);
        }
        f32x4 aq = 0.0f, ak = 0.0f, avv = 0.0f;
#pragma unroll
        for (int ks = 0; ks < 2; ks++) {
            aq = MFMA(uq[ks], tf[0][ks], aq);  // swapped: lane->m, reg->n
            ak = MFMA(uk[ks], tf[1][ks], ak);
            avv = MFMA(tf[2][ks], uvh[ks], avv);  // unswapped: lane->n, reg->m
            avv = MFMA(tf[2][ks], uvl[ks], avv);
            avv = MFMA(tfl[ks], uvh[ks], avv);
        }
        // q,k: [B,H,T,D], lane row tt, regs run along dd -> packed 8B
        const int tt = mt + lr;
        const int nq = tn * 16 + lk * 4;
        const int hhq = nq >> 6, ddq = nq & 63;
        short4v pq, pk;
#pragma unroll
        for (int i = 0; i < 4; i++) { pq[i] = f2bf(aq[i]); pk[i] = f2bf(ak[i]); }
        *(short4v*)(qb + ((size_t)(bb * NH + hhq) * NT + tt) * ND + ddq) = pq;
        *(short4v*)(kb + ((size_t)(bb * NH + hhq) * NT + tt) * ND + ddq) = pk;
        // v: [B,H,D,T], lane col n -> (hh,dd), regs run along tt -> packed 8B
        const int n = tn * 16 + lr;
        const int hhv = n >> 6, ddv = n & 63;
        const int tv = mt + lk * 4;
        short4v pv;
#pragma unroll
        for (int i = 0; i < 4; i++) pv[i] = f2bf(avv[i]);
        *(short4v*)(vtb + ((size_t)(bb * NH + hhv) * ND + ddv) * NT + tv) = pv;
    }
}

// ---- fused c-path: R14: 512 blocks x 16 rows, 256 threads (4 waves).
__global__ __launch_bounds__(256, 4) void k_cout(const short* __restrict__ Yb,
                                                 const short* __restrict__ Whi, const short* __restrict__ Wlo,
                                                 float* __restrict__ Out) {
    __shared__ __align__(16) char Yl[2][8192];  // 16 rows x 256 bf16, swizzled, dbuf
    __shared__ __align__(16) short tyhi[16 * 72];
    __shared__ __align__(16) short tylo[16 * 72];
    const int tid = threadIdx.x;
    const int w = tid >> 6, l = tid & 63;
    const int lr = l & 15, lk = l >> 4;
    const int g = w;
    const int mb = blockIdx.x * 16;
    const short* cVfh = Whi + 3 * 65536;
    const short* cVfl = Wlo + 3 * 65536;
    const short* cUfh = Whi + 7 * 65536;
    const short* cUfl = Wlo + 7 * 65536;

    auto stageY = [&](int buf, int win) {
#pragma unroll
        for (int q = 0; q < 2; q++) {
            const int r = q * 8 + w * 2 + (l >> 5);
            const int c = l & 31;
            const int sc16 = c ^ (r & 15);
            const short* gp = Yb + (size_t)(mb + r) * NC + win * 256 + sc16 * 8;
            gll16(gp, (char*)Yl[buf] + q * 4096 + w * 1024);
        }
    };

    // phase 1: ty tile g (2-term), full K (4 windows x 8 steps)
    const int tV = g * 32;
    f32x4 acc = 0.0f;
    const int xrow = lr * 512;
    stageY(0, 0);
    for (int win = 0; win < 4; ++win) {
        const int buf = win & 1;
        __syncthreads();
        if (win < 3) stageY(buf ^ 1, win + 1);
        const char* YB = Yl[buf];
#pragma unroll
        for (int kk = 0; kk < 8; ++kk) {
            const short8 ah = *(const short8*)(YB + xrow + ((((kk * 4 + lk)) ^ lr) << 4));
            const int s = win * 8 + kk;
            const short8 wh = *(const short8*)(cVfh + (size_t)((tV + s) * 64 + l) * 8);
            const short8 wl = *(const short8*)(cVfl + (size_t)((tV + s) * 64 + l) * 8);
            acc = MFMA(ah, wh, acc);
            acc = MFMA(ah, wl, acc);
        }
    }
    // phase 2: own tile -> tyhi/tylo
#pragma unroll
    for (int i = 0; i < 4; i++) {
        const int row = lk * 4 + i;
        const short h = f2bf(acc[i]);
        tyhi[row * 72 + g * 16 + lr] = h;
        tylo[row * 72 + g * 16 + lr] = f2bf(acc[i] - bf2f(h));
    }
    __syncthreads();
    // phase 3: out = ty @ cU^T (3-term), 16 n-tiles per wave, float4 stores
    short8 th[2], tl[2];
#pragma unroll
    for (int ks = 0; ks < 2; ks++) {
        th[ks] = *(const short8*)(tyhi + lr * 72 + ks * 32 + lk * 8);
        tl[ks] = *(const short8*)(tylo + lr * 72 + ks * 32 + lk * 8);
    }
#pragma unroll 2
    for (int nt = 0; nt < 16; nt++) {
        const int tn = w * 16 + nt;
        short8 uh[2], ul[2];
#pragma unroll
        for (int ks = 0; ks < 2; ks++) {
            const size_t off2 = (size_t)((tn * 2 + ks) * 64 + l) * 8;
            uh[ks] = *(const short8*)(cUfh + off2);
            ul[ks] = *(const short8*)(cUfl + off2);
        }
        f32x4 a = 0.0f;
#pragma unroll
        for (int ks = 0; ks < 2; ks++) {
            a = MFMA(uh[ks], th[ks], a);
            a = MFMA(ul[ks], th[ks], a);
            a = MFMA(uh[ks], tl[ks], a);
        }
        const int mm = mb + lr;
        const int n = tn * 16 + lk * 4;
        *(float4v*)(Out + (size_t)mm * NC + n) = *(float4v*)&a;
    }
}

// swizzled LDS fragment read: tile [64][64] bf16, row stride 128B, byte ^ (row&7)<<4
__device__ __forceinline__ short8 lds_frag(const short* base, int row, int cb) {
    return *(const short8*)((const char*)base + (((row << 7) + cb) ^ ((row & 7) << 4)));
}

// ---- causal flash attention (R11 version, reverted). grid (8, B*H) XCD-swizzled;
// 4 waves. Block j covers A rows [128j,128j+128) and B rows [1920-128j,+128);
// wave w owns 32 rows (2 x 16-row frags) of EACH. Shared K/V frag reads feed
// both frags. Fixed-shift softmax (P = 2^(S-16) via MFMA C-init).
__global__ __launch_bounds__(256, 2) void k_attn(const short* __restrict__ Qm,
                                                 const short* __restrict__ Km,
                                                 const short* __restrict__ Vt,
                                                 short* __restrict__ Y) {
    __shared__ __align__(16) short Kl[2][64 * 64];  // 16 KB dbuf, swizzled layout
    __shared__ __align__(16) short Vl[2][64 * 64];  // 16 KB
    __shared__ __align__(16) short Pl[8 * 1024];    // 4 waves x 2 frags x 16x64
    const int tid = threadIdx.x;
    const int w = tid >> 6, l = tid & 63;
    const int lr = l & 15, lk = l >> 4;
    // bijective XCD-chunk swizzle: each XCD gets 8 complete bh's (K/V L2-resident)
    const int lin = blockIdx.y * 8 + blockIdx.x;    // 512 blocks
    const int nl = (lin & 7) * 64 + (lin >> 3);
    const int j = nl & 7;
    const int bh = nl >> 3;
    const int ntile = 32 - 2 * j;
    const int qA0 = 128 * j + w * 32;
    const int qB0 = (1920 - 128 * j) + w * 32;
    const int diagA = 2 * j + (w >> 1);             // wave-uniform diag tiles
    const int diagB = 30 - 2 * j + (w >> 1);

    const short* Kb = Km + (size_t)bh * NT * ND;
    const short* Vb = Vt + (size_t)bh * ND * NT;

    short8 qfA[2][2], qfB[2][2];  // [frag][ks]
#pragma unroll
    for (int f = 0; f < 2; f++) {
#pragma unroll
        for (int ks = 0; ks < 2; ks++) {
            qfA[f][ks] = *(const short8*)(Qm + ((size_t)bh * NT + qA0 + f * 16 + lr) * ND + ks * 32 + lk * 8);
            qfB[f][ks] = *(const short8*)(Qm + ((size_t)bh * NT + qB0 + f * 16 + lr) * ND + ks * 32 + lk * 8);
        }
    }

    // gll16 staging: LDS dest linear, global src pre-swizzled
    const int grow8 = w * 8 + (l >> 3);
    const int gcolb = (((l & 7) ^ ((l >> 3) & 7)) << 4);
    auto stage = [&](int buf, int kv0) {
        const char* kp = (const char*)Kb + (((size_t)(kv0 + grow8)) << 7) + gcolb;
        const char* vp = (const char*)Vb + (size_t)grow8 * (NT * 2) + kv0 * 2 + gcolb;
        char* kl = (char*)Kl[buf] + w * 1024;
        char* vl = (char*)Vl[buf] + w * 1024;
        gll16(kp, kl);
        gll16(kp + (32 << 7), kl + 4096);
        gll16(vp, vl);
        gll16(vp + (size_t)32 * NT * 2, vl + 4096);
    };

    f32x4 lsA[2], lsB[2];
    f32x4 oA[2][4], oB[2][4];
#pragma unroll
    for (int f = 0; f < 2; f++) {
        lsA[f] = 0.0f;
        lsB[f] = 0.0f;
#pragma unroll
        for (int dt = 0; dt < 4; dt++) { oA[f][dt] = 0.0f; oB[f][dt] = 0.0f; }
    }

    auto computeG = [&](const short8 (&qf)[2][2], f32x4 (&ls)[2], f32x4 (&o)[2][4],
                        const short* KlB, const short* VlB, bool diag) {
        // S^T - 16 via C-init; both frags share each K fragment read
        f32x4 sa[2][4];
#pragma unroll
        for (int f = 0; f < 2; f++)
#pragma unroll
            for (int nt = 0; nt < 4; nt++) sa[f][nt] = -16.0f;
        __builtin_amdgcn_s_setprio(1);
#pragma unroll
        for (int ks = 0; ks < 2; ks++) {
#pragma unroll
            for (int nt = 0; nt < 4; nt++) {
                const short8 kf = lds_frag(KlB, nt * 16 + lr, ks * 64 + lk * 16);
                sa[0][nt] = MFMA(kf, qf[0][ks], sa[0][nt]);
                sa[1][nt] = MFMA(kf, qf[1][ks], sa[1][nt]);
            }
        }
        __builtin_amdgcn_s_setprio(0);
        if (diag) {
#pragma unroll
            for (int f = 0; f < 2; f++) {
                const int qrel = (w & 1) * 32 + f * 16 + lr;
#pragma unroll
                for (int nt = 0; nt < 4; nt++) {
                    const int kvb = nt * 16 + lk * 4;
#pragma unroll
                    for (int i = 0; i < 4; i++)
                        if (kvb + i > qrel) sa[f][nt][i] = -1e30f;
                }
            }
        }
        // exp2 + l-partials + P^T -> per-wave-per-frag LDS
#pragma unroll
        for (int f = 0; f < 2; f++) {
            char* plbf = (char*)Pl + w * 4096 + f * 2048;
#pragma unroll
            for (int nt = 0; nt < 4; nt++) {
                f32x4 sv;
#pragma unroll
                for (int i = 0; i < 4; i++) sv[i] = exp2_(sa[f][nt][i]);
                ls[f] += sv;
                short4v pk;
#pragma unroll
                for (int i = 0; i < 4; i++) pk[i] = f2bf(sv[i]);
                *(short4v*)(plbf + (((lr << 7) + ((nt * 16 + lk * 4) << 1)) ^ ((lr & 7) << 4))) = pk;
            }
        }
        short8 pb[2][2];
#pragma unroll
        for (int f = 0; f < 2; f++) {
            const char* plbf = (const char*)Pl + w * 4096 + f * 2048;
            pb[f][0] = *(const short8*)(plbf + (((lr << 7) + ((lk * 8) << 1)) ^ ((lr & 7) << 4)));
            pb[f][1] = *(const short8*)(plbf + (((lr << 7) + ((32 + lk * 8) << 1)) ^ ((lr & 7) << 4)));
        }
        // O^T += V^T . P ; both frags share each V fragment read
        __builtin_amdgcn_s_setprio(1);
#pragma unroll
        for (int ks = 0; ks < 2; ks++) {
#pragma unroll
            for (int dt = 0; dt < 4; dt++) {
                const short8 vf = lds_frag(VlB, dt * 16 + lr, ks * 64 + lk * 16);
                o[0][dt] = MFMA(vf, pb[0][ks], o[0][dt]);
                o[1][dt] = MFMA(vf, pb[1][ks], o[1][dt]);
            }
        }
        __builtin_amdgcn_s_setprio(0);
    };

    stage(0, 0);  // tile 0 -> buf 0
    for (int it = 0; it < ntile; ++it) {
        const int buf = it & 1;
        __syncthreads();  // drains this tile's gll16 (vmcnt) + syncs
        if (it + 1 < ntile) stage(buf ^ 1, (it + 1) * 64);  // overlaps compute
        const short* KlB = Kl[buf];
        const short* VlB = Vl[buf];
        if (it <= diagA) computeG(qfA, lsA, oA, KlB, VlB, it == diagA);
        if (it <= diagB) computeG(qfB, lsB, oB, KlB, VlB, it == diagB);
    }

    const int b = bh >> 4, h = bh & 15;
#pragma unroll
    for (int f = 0; f < 2; f++) {
        float lA = (lsA[f][0] + lsA[f][1]) + (lsA[f][2] + lsA[f][3]);
        float lB = (lsB[f][0] + lsB[f][1]) + (lsB[f][2] + lsB[f][3]);
        lA += __shfl_xor(lA, 16);
        lA += __shfl_xor(lA, 32);
        lB += __shfl_xor(lB, 16);
        lB += __shfl_xor(lB, 32);
        const float invA = 1.0f / lA, invB = 1.0f / lB;
        short* ypA = Y + ((size_t)b * NT + (qA0 + f * 16 + lr)) * NC + h * ND;
        short* ypB = Y + ((size_t)b * NT + (qB0 + f * 16 + lr)) * NC + h * ND;
#pragma unroll
        for (int dt = 0; dt < 4; dt++) {
            short4v ya, yb2;
#pragma unroll
            for (int i = 0; i < 4; i++) {
                ya[i] = f2bf(oA[f][dt][i] * invA);
                yb2[i] = f2bf(oB[f][dt][i] * invB);
            }
            *(short4v*)(ypA + dt * 16 + lk * 4) = ya;
            *(short4v*)(ypB + dt * 16 + lk * 4) = yb2;
        }
    }
}

extern "C" void kernel_launch(void* const* d_in, const int* in_sizes, int n_in,
                              void* d_out, int out_size, void* d_ws, size_t ws_size,
                              hipStream_t stream) {
    const float* x = (const float*)d_in[0];
    const float* qU = (const float*)d_in[1];
    const float* qV = (const float*)d_in[2];
    const float* kU = (const float*)d_in[3];
    const float* kV = (const float*)d_in[4];
    const float* vU = (const float*)d_in[5];
    const float* vV = (const float*)d_in[6];
    const float* cU = (const float*)d_in[7];
    const float* cV = (const float*)d_in[8];
    float* out = (float*)d_out;

    char* ws = (char*)d_ws;
    size_t off = 0;
    auto take = [&](size_t bytes) {
        char* p = ws + off;
        off += (bytes + 255) & ~(size_t)255;
        return p;
    };
    short* Whi = (short*)take(8 * 65536 * 2);
    short* Wlo = (short*)take(8 * 65536 * 2);
    short* qb = (short*)take((size_t)NM * NC * 2);
    short* kb = (short*)take((size_t)NM * NC * 2);
    short* vtb = (short*)take((size_t)NM * NC * 2);
    short* yb = (short*)take((size_t)NM * NC * 2);

    k_prep<<<256, 256, 0, stream>>>(qV, kV, vV, cV, qU, kU, vU, cU, Whi, Wlo);
    k_qkv<<<512, 256, 0, stream>>>(x, Whi, Wlo, qb, kb, vtb);
    k_attn<<<dim3(8, NB * NH), 256, 0, stream>>>(qb, kb, vtb, yb);
    k_cout<<<512, 256, 0, stream>>>(yb, Whi, Wlo, out);
}

// Round 16
// 117.699 us; speedup vs baseline: 1.6645x; 1.0676x over previous
//
#include <hip/hip_runtime.h>
#include <hip/hip_bf16.h>
#include <math.h>

// HarmonicCausalSelfAttention: B=4 T=2048 C=1024 H=16 R=64 D=64, alpha=0.7
// R15 pipeline (4 launches) — best-of-each-round composition:
//   k_prep : weights -> fragment-linear bf16 hi/lo (R10, unchanged since)
//   k_qkv  : fused x->(t)->q,k,v (R10 verbatim: 256 blocks x 32 rows, 8 waves —
//            best measured; R14's 16-row variant doubled weight transactions)
//   k_attn : causal flash attn (R11 verbatim: A/B-paired 32-q-rows/wave, shared
//            K/V frag reads, dbuf gll16 staging, XCD swizzle, fixed-shift softmax)
//   k_cout : fused y->(ty)->out (R10 verbatim)

#define NB 4
#define NT 2048
#define NC 1024
#define NH 16
#define NR 64
#define ND 64
#define NM (NB * NT)  // 8192

typedef __attribute__((ext_vector_type(8))) short short8;
typedef __attribute__((ext_vector_type(4))) short short4v;
typedef __attribute__((ext_vector_type(4))) float f32x4;
typedef __attribute__((ext_vector_type(4))) float float4v;
typedef __attribute__((ext_vector_type(4))) int int4v;

__device__ __forceinline__ short f2bf(float f) {
    union { __hip_bfloat16 h; short s; } u;
    u.h = __float2bfloat16(f);
    return u.s;
}
__device__ __forceinline__ float bf2f(short s) {
    union { short s; __hip_bfloat16 h; } u;
    u.s = s;
    return __bfloat162float(u.h);
}
__device__ __forceinline__ f32x4 MFMA(short8 a, short8 b, f32x4 c) {
    return __builtin_amdgcn_mfma_f32_16x16x32_bf16(a, b, c, 0, 0, 0);
}
__device__ __forceinline__ float exp2_(float x) {
#if __has_builtin(__builtin_amdgcn_exp2f)
    return __builtin_amdgcn_exp2f(x);
#else
    return exp2f(x);
#endif
}

// async global->LDS, 16B per lane (LDS dest = wave-uniform base + lane*16)
typedef const __attribute__((address_space(1))) unsigned int* gas_ptr;
typedef __attribute__((address_space(3))) unsigned int* las_ptr;
__device__ __forceinline__ void gll16(const void* g, void* l) {
    __builtin_amdgcn_global_load_lds((gas_ptr)g, (las_ptr)l, 16, 0, 0);
}

// ---- weight prep -> fragment-linear layout.
// mats 0-3 = qV,kV,vV,cV ([64 r][1024 c], scale (r+1)^-0.7):
//   fragment f = (nt*32+s)*64+l holds rows nt*16+(l&15), cols s*32+(l>>4)*8 .. +8
// mats 4-7 = qU,kU,vU,cU ([1024 n][64 r]; qU additionally x 0.125*log2e):
//   fragment f = (tn*2+ks)*64+l holds rows tn*16+(l&15), cols ks*32+(l>>4)*8 .. +8
__global__ __launch_bounds__(256) void k_prep(const float* __restrict__ qV, const float* __restrict__ kV,
                                              const float* __restrict__ vV, const float* __restrict__ cV,
                                              const float* __restrict__ qU, const float* __restrict__ kU,
                                              const float* __restrict__ vU, const float* __restrict__ cU,
                                              short* __restrict__ Whi, short* __restrict__ Wlo) {
    const int idx = blockIdx.x * 256 + threadIdx.x;  // 0..65535
    const int mat = idx >> 13;                       // 8 mats x 8192 fragments
    const int f = idx & 8191;
    const int l = f & 63;
    const int rest = f >> 6;  // 0..127
    const float* src;
    switch (mat) {
        case 0: src = qV; break;
        case 1: src = kV; break;
        case 2: src = vV; break;
        case 3: src = cV; break;
        case 4: src = qU; break;
        case 5: src = kU; break;
        case 6: src = vU; break;
        default: src = cU; break;
    }
    int row, col, stride;
    if (mat < 4) {
        const int s = rest & 31, nt = rest >> 5;
        row = nt * 16 + (l & 15);
        col = s * 32 + (l >> 4) * 8;
        stride = NC;
    } else {
        const int ks = rest & 1, tn = rest >> 1;
        row = tn * 16 + (l & 15);
        col = ks * 32 + (l >> 4) * 8;
        stride = NR;
    }
    float sc = 1.0f;
    if (mat < 4) sc = powf((float)(row + 1), -0.7f);
    if (mat == 4) sc = 0.125f * 1.44269504088896f;  // fold scale and log2(e)
    const float* p = src + (size_t)row * stride + col;
    const float4v a = *(const float4v*)p;
    const float4v b = *(const float4v*)(p + 4);
    float v[8] = {a[0], a[1], a[2], a[3], b[0], b[1], b[2], b[3]};
    short* oh = Whi + (size_t)mat * 65536 + (size_t)f * 8;
    short* ol = Wlo + (size_t)mat * 65536 + (size_t)f * 8;
    short4v h0, h1, l0, l1;
#pragma unroll
    for (int j = 0; j < 8; j++) {
        const float fv = v[j] * sc;
        const short h = f2bf(fv);
        const short lo = f2bf(fv - bf2f(h));
        if (j < 4) { h0[j] = h; l0[j] = lo; } else { h1[j - 4] = h; l1[j - 4] = lo; }
    }
    *(short4v*)oh = h0;
    *(short4v*)(oh + 4) = h1;
    *(short4v*)ol = l0;
    *(short4v*)(ol + 4) = l1;
}

// ---- fused q/k/v (R10 verbatim): 256 blocks x 32 m-rows, 512 threads (8 waves).
// wave = (g = w&3, mg = w>>2). Phase1: g -> {q-or-k tiles (g&1)*2,+1 ; v tile g},
// m-group mg, FULL K (32 steps over 8 staged X windows). Fragment-linear weights.
// Phase2: in-register hi/lo -> Thi[32][200], Tlov[32][72]. Phase3: n-eighth/wave.
__global__ __launch_bounds__(512, 2) void k_qkv(const float* __restrict__ X,
                                                const short* __restrict__ Whi, const short* __restrict__ Wlo,
                                                short* __restrict__ qb, short* __restrict__ kb,
                                                short* __restrict__ vtb) {
    __shared__ __align__(16) char Xl[2][16384];  // 32 rows x 128 f32, swizzled, dbuf
    __shared__ __align__(16) short Thi[32 * 200];
    __shared__ __align__(16) short Tlov[32 * 72];
    const int tid = threadIdx.x;
    const int w = tid >> 6, l = tid & 63;
    const int lr = l & 15, lk = l >> 4;
    const int g = w & 3, mg = w >> 2;
    const int mb = blockIdx.x * 32;

    // stage one 128-f32-col window (16 KB): 2 gll16/thread, coalesced.
    // LDS chunk (r, c) holds global 16B chunk (r, c ^ (r&15)).
    auto stageX = [&](int buf, int win) {
#pragma unroll
        for (int q = 0; q < 2; q++) {
            const int r = q * 16 + w * 2 + (l >> 5);
            const int c = l & 31;
            const int sc16 = c ^ (r & 15);
            const float* gp = X + (size_t)(mb + r) * NC + win * 128 + sc16 * 4;
            gll16(gp, (char*)Xl[buf] + q * 8192 + w * 1024);
        }
    };

    const short* Wqk_f = (g < 2) ? Whi : (Whi + 65536);
    const int tA = ((g & 1) * 2) * 32;  // (tile ntA) * 32 steps
    const int tB = tA + 32;
    const int tV = g * 32;
    const short* vfh = Whi + 2 * 65536;
    const short* vfl = Wlo + 2 * 65536;

    f32x4 a0 = 0.0f, a1 = 0.0f, av = 0.0f;
    const int xrow = (mg * 16 + lr) * 512;
    stageX(0, 0);
    for (int win = 0; win < 8; ++win) {
        const int buf = win & 1;
        __syncthreads();  // drains this window's gll16 + syncs buffers
        if (win < 7) stageX(buf ^ 1, win + 1);
        const char* XB = Xl[buf];
#pragma unroll
        for (int kk = 0; kk < 4; ++kk) {
            const int cb = kk * 8 + lk * 2;
            const float4v xa = *(const float4v*)(XB + xrow + ((cb ^ lr) << 4));
            const float4v xb = *(const float4v*)(XB + xrow + (((cb + 1) ^ lr) << 4));
            float xv[8] = {xa[0], xa[1], xa[2], xa[3], xb[0], xb[1], xb[2], xb[3]};
            short8 xh, xl8;
#pragma unroll
            for (int jj = 0; jj < 8; jj++) {
                const short h = f2bf(xv[jj]);
                xh[jj] = h;
                xl8[jj] = f2bf(xv[jj] - bf2f(h));
            }
            const int s = win * 4 + kk;
            const short8 wa = *(const short8*)(Wqk_f + (size_t)((tA + s) * 64 + l) * 8);
            const short8 wb = *(const short8*)(Wqk_f + (size_t)((tB + s) * 64 + l) * 8);
            const short8 wvh = *(const short8*)(vfh + (size_t)((tV + s) * 64 + l) * 8);
            const short8 wvl = *(const short8*)(vfl + (size_t)((tV + s) * 64 + l) * 8);
            a0 = MFMA(xh, wa, a0);
            a1 = MFMA(xh, wb, a1);
            av = MFMA(xh, wvh, av);
            av = MFMA(xh, wvl, av);
            av = MFMA(xl8, wvh, av);
        }
    }
    // ---- phase 2: own-acc convert -> Thi/Tlov (no cross-wave sums)
    {
        const int p = g >> 1;
        const int colA = p * 64 + (g & 1) * 32 + lr;
        const int colB = colA + 16;
        const int colV = 128 + g * 16 + lr;
#pragma unroll
        for (int i = 0; i < 4; i++) {
            const int row = mg * 16 + lk * 4 + i;
            Thi[row * 200 + colA] = f2bf(a0[i]);
            Thi[row * 200 + colB] = f2bf(a1[i]);
            const short hv = f2bf(av[i]);
            Thi[row * 200 + colV] = hv;
            Tlov[row * 72 + g * 16 + lr] = f2bf(av[i] - bf2f(hv));
        }
    }
    __syncthreads();
    // ---- phase 3: this wave's n-eighth, both m-groups
    const short* qUf = Whi + 4 * 65536;
    const short* kUf = Whi + 5 * 65536;
    const short* vUfh = Whi + 6 * 65536;
    const short* vUfl = Wlo + 6 * 65536;
    short8 tf[2][3][2];  // [mg][path][ks] hi
    short8 tfl[2][2];    // [mg][ks] v-lo
#pragma unroll
    for (int m2 = 0; m2 < 2; m2++) {
        const int trow = m2 * 16 + lr;
#pragma unroll
        for (int ks = 0; ks < 2; ks++) {
#pragma unroll
            for (int p = 0; p < 3; p++)
                tf[m2][p][ks] = *(const short8*)(Thi + trow * 200 + p * 64 + ks * 32 + lk * 8);
            tfl[m2][ks] = *(const short8*)(Tlov + trow * 72 + ks * 32 + lk * 8);
        }
    }
    const int bb = mb >> 11, mt = mb & (NT - 1);
#pragma unroll 2
    for (int nt = 0; nt < 8; nt++) {
        const int tn = w * 8 + nt;
        short8 uq[2], uk[2], uvh[2], uvl[2];
#pragma unroll
        for (int ks = 0; ks < 2; ks++) {
            const size_t off2 = (size_t)((tn * 2 + ks) * 64 + l) * 8;
            uq[ks] = *(const short8*)(qUf + off2);
            uk[ks] = *(const short8*)(kUf + off2);
            uvh[ks] = *(const short8*)(vUfh + off2);
            uvl[ks] = *(const short8*)(vUfl + off2);
        }
#pragma unroll
        for (int m2 = 0; m2 < 2; m2++) {
            f32x4 aq = 0.0f, ak = 0.0f, avv = 0.0f;
#pragma unroll
            for (int ks = 0; ks < 2; ks++) {
                aq = MFMA(uq[ks], tf[m2][0][ks], aq);  // swapped: lane->m, reg->n
                ak = MFMA(uk[ks], tf[m2][1][ks], ak);
                avv = MFMA(tf[m2][2][ks], uvh[ks], avv);  // unswapped: lane->n, reg->m
                avv = MFMA(tf[m2][2][ks], uvl[ks], avv);
                avv = MFMA(tfl[m2][ks], uvh[ks], avv);
            }
            // q,k: [B,H,T,D], lane row tt, regs run along dd -> packed 8B
            const int tt = mt + m2 * 16 + lr;
            const int nq = tn * 16 + lk * 4;
            const int hhq = nq >> 6, ddq = nq & 63;
            short4v pq, pk;
#pragma unroll
            for (int i = 0; i < 4; i++) { pq[i] = f2bf(aq[i]); pk[i] = f2bf(ak[i]); }
            *(short4v*)(qb + ((size_t)(bb * NH + hhq) * NT + tt) * ND + ddq) = pq;
            *(short4v*)(kb + ((size_t)(bb * NH + hhq) * NT + tt) * ND + ddq) = pk;
            // v: [B,H,D,T], lane col n -> (hh,dd), regs run along tt -> packed 8B
            const int n = tn * 16 + lr;
            const int hhv = n >> 6, ddv = n & 63;
            const int tv = mt + m2 * 16 + lk * 4;
            short4v pv;
#pragma unroll
            for (int i = 0; i < 4; i++) pv[i] = f2bf(avv[i]);
            *(short4v*)(vtb + ((size_t)(bb * NH + hhv) * ND + ddv) * NT + tv) = pv;
        }
    }
}

// ---- fused c-path (R10 verbatim): 256 blocks x 32 rows, 512 threads.
__global__ __launch_bounds__(512, 2) void k_cout(const short* __restrict__ Yb,
                                                 const short* __restrict__ Whi, const short* __restrict__ Wlo,
                                                 float* __restrict__ Out) {
    __shared__ __align__(16) char Yl[2][16384];  // 32 rows x 256 bf16, swizzled, dbuf
    __shared__ __align__(16) short tyhi[32 * 72];
    __shared__ __align__(16) short tylo[32 * 72];
    const int tid = threadIdx.x;
    const int w = tid >> 6, l = tid & 63;
    const int lr = l & 15, lk = l >> 4;
    const int g = w & 3, mg = w >> 2;
    const int mb = blockIdx.x * 32;
    const short* cVfh = Whi + 3 * 65536;
    const short* cVfl = Wlo + 3 * 65536;
    const short* cUfh = Whi + 7 * 65536;
    const short* cUfl = Wlo + 7 * 65536;

    auto stageY = [&](int buf, int win) {
#pragma unroll
        for (int q = 0; q < 2; q++) {
            const int r = q * 16 + w * 2 + (l >> 5);
            const int c = l & 31;
            const int sc16 = c ^ (r & 15);
            const short* gp = Yb + (size_t)(mb + r) * NC + win * 256 + sc16 * 8;
            gll16(gp, (char*)Yl[buf] + q * 8192 + w * 1024);
        }
    };

    // phase 1: ty tile g, m-group mg, full K (4 windows x 8 steps), 2-term
    const int tV = g * 32;
    f32x4 acc = 0.0f;
    const int xrow = (mg * 16 + lr) * 512;
    stageY(0, 0);
    for (int win = 0; win < 4; ++win) {
        const int buf = win & 1;
        __syncthreads();
        if (win < 3) stageY(buf ^ 1, win + 1);
        const char* YB = Yl[buf];
#pragma unroll
        for (int kk = 0; kk < 8; ++kk) {
            const short8 ah = *(const short8*)(YB + xrow + ((((kk * 4 + lk)) ^ lr) << 4));
            const int s = win * 8 + kk;
            const short8 wh = *(const short8*)(cVfh + (size_t)((tV + s) * 64 + l) * 8);
            const short8 wl = *(const short8*)(cVfl + (size_t)((tV + s) * 64 + l) * 8);
            acc = MFMA(ah, wh, acc);
            acc = MFMA(ah, wl, acc);
        }
    }
    // phase 2: own tile -> tyhi/tylo
#pragma unroll
    for (int i = 0; i < 4; i++) {
        const int row = mg * 16 + lk * 4 + i;
        const short h = f2bf(acc[i]);
        tyhi[row * 72 + g * 16 + lr] = h;
        tylo[row * 72 + g * 16 + lr] = f2bf(acc[i] - bf2f(h));
    }
    __syncthreads();
    // phase 3: out = ty @ cU^T (3-term), n-eighth per wave, both m-groups
    short8 th[2][2], tl[2][2];
#pragma unroll
    for (int m2 = 0; m2 < 2; m2++) {
        const int trow = m2 * 16 + lr;
#pragma unroll
        for (int ks = 0; ks < 2; ks++) {
            th[m2][ks] = *(const short8*)(tyhi + trow * 72 + ks * 32 + lk * 8);
            tl[m2][ks] = *(const short8*)(tylo + trow * 72 + ks * 32 + lk * 8);
        }
    }
#pragma unroll 2
    for (int nt = 0; nt < 8; nt++) {
        const int tn = w * 8 + nt;
        short8 uh[2], ul[2];
#pragma unroll
        for (int ks = 0; ks < 2; ks++) {
            const size_t off2 = (size_t)((tn * 2 + ks) * 64 + l) * 8;
            uh[ks] = *(const short8*)(cUfh + off2);
            ul[ks] = *(const short8*)(cUfl + off2);
        }
#pragma unroll
        for (int m2 = 0; m2 < 2; m2++) {
            f32x4 a = 0.0f;
#pragma unroll
            for (int ks = 0; ks < 2; ks++) {
                a = MFMA(uh[ks], th[m2][ks], a);
                a = MFMA(ul[ks], th[m2][ks], a);
                a = MFMA(uh[ks], tl[m2][ks], a);
            }
            const int mm = mb + m2 * 16 + lr;
            const int n = tn * 16 + lk * 4;
            *(float4v*)(Out + (size_t)mm * NC + n) = *(float4v*)&a;
        }
    }
}

// swizzled LDS fragment read: tile [64][64] bf16, row stride 128B, byte ^ (row&7)<<4
__device__ __forceinline__ short8 lds_frag(const short* base, int row, int cb) {
    return *(const short8*)((const char*)base + (((row << 7) + cb) ^ ((row & 7) << 4)));
}

// ---- causal flash attention (R11 verbatim). grid (8, B*H) XCD-swizzled;
// 4 waves. Block j covers A rows [128j,128j+128) and B rows [1920-128j,+128);
// wave w owns 32 rows (2 x 16-row frags) of EACH. Shared K/V frag reads feed
// both frags. Fixed-shift softmax (P = 2^(S-16) via MFMA C-init).
__global__ __launch_bounds__(256, 2) void k_attn(const short* __restrict__ Qm,
                                                 const short* __restrict__ Km,
                                                 const short* __restrict__ Vt,
                                                 short* __restrict__ Y) {
    __shared__ __align__(16) short Kl[2][64 * 64];  // 16 KB dbuf, swizzled layout
    __shared__ __align__(16) short Vl[2][64 * 64];  // 16 KB
    __shared__ __align__(16) short Pl[8 * 1024];    // 4 waves x 2 frags x 16x64
    const int tid = threadIdx.x;
    const int w = tid >> 6, l = tid & 63;
    const int lr = l & 15, lk = l >> 4;
    // bijective XCD-chunk swizzle: each XCD gets 8 complete bh's (K/V L2-resident)
    const int lin = blockIdx.y * 8 + blockIdx.x;    // 512 blocks
    const int nl = (lin & 7) * 64 + (lin >> 3);
    const int j = nl & 7;
    const int bh = nl >> 3;
    const int ntile = 32 - 2 * j;
    const int qA0 = 128 * j + w * 32;
    const int qB0 = (1920 - 128 * j) + w * 32;
    const int diagA = 2 * j + (w >> 1);             // wave-uniform diag tiles
    const int diagB = 30 - 2 * j + (w >> 1);

    const short* Kb = Km + (size_t)bh * NT * ND;
    const short* Vb = Vt + (size_t)bh * ND * NT;

    short8 qfA[2][2], qfB[2][2];  // [frag][ks]
#pragma unroll
    for (int f = 0; f < 2; f++) {
#pragma unroll
        for (int ks = 0; ks < 2; ks++) {
            qfA[f][ks] = *(const short8*)(Qm + ((size_t)bh * NT + qA0 + f * 16 + lr) * ND + ks * 32 + lk * 8);
            qfB[f][ks] = *(const short8*)(Qm + ((size_t)bh * NT + qB0 + f * 16 + lr) * ND + ks * 32 + lk * 8);
        }
    }

    // gll16 staging: LDS dest linear, global src pre-swizzled
    const int grow8 = w * 8 + (l >> 3);
    const int gcolb = (((l & 7) ^ ((l >> 3) & 7)) << 4);
    auto stage = [&](int buf, int kv0) {
        const char* kp = (const char*)Kb + (((size_t)(kv0 + grow8)) << 7) + gcolb;
        const char* vp = (const char*)Vb + (size_t)grow8 * (NT * 2) + kv0 * 2 + gcolb;
        char* kl = (char*)Kl[buf] + w * 1024;
        char* vl = (char*)Vl[buf] + w * 1024;
        gll16(kp, kl);
        gll16(kp + (32 << 7), kl + 4096);
        gll16(vp, vl);
        gll16(vp + (size_t)32 * NT * 2, vl + 4096);
    };

    f32x4 lsA[2], lsB[2];
    f32x4 oA[2][4], oB[2][4];
#pragma unroll
    for (int f = 0; f < 2; f++) {
        lsA[f] = 0.0f;
        lsB[f] = 0.0f;
#pragma unroll
        for (int dt = 0; dt < 4; dt++) { oA[f][dt] = 0.0f; oB[f][dt] = 0.0f; }
    }

    auto computeG = [&](const short8 (&qf)[2][2], f32x4 (&ls)[2], f32x4 (&o)[2][4],
                        const short* KlB, const short* VlB, bool diag) {
        // S^T - 16 via C-init; both frags share each K fragment read
        f32x4 sa[2][4];
#pragma unroll
        for (int f = 0; f < 2; f++)
#pragma unroll
            for (int nt = 0; nt < 4; nt++) sa[f][nt] = -16.0f;
        __builtin_amdgcn_s_setprio(1);
#pragma unroll
        for (int ks = 0; ks < 2; ks++) {
#pragma unroll
            for (int nt = 0; nt < 4; nt++) {
                const short8 kf = lds_frag(KlB, nt * 16 + lr, ks * 64 + lk * 16);
                sa[0][nt] = MFMA(kf, qf[0][ks], sa[0][nt]);
                sa[1][nt] = MFMA(kf, qf[1][ks], sa[1][nt]);
            }
        }
        __builtin_amdgcn_s_setprio(0);
        if (diag) {
#pragma unroll
            for (int f = 0; f < 2; f++) {
                const int qrel = (w & 1) * 32 + f * 16 + lr;
#pragma unroll
                for (int nt = 0; nt < 4; nt++) {
                    const int kvb = nt * 16 + lk * 4;
#pragma unroll
                    for (int i = 0; i < 4; i++)
                        if (kvb + i > qrel) sa[f][nt][i] = -1e30f;
                }
            }
        }
        // exp2 + l-partials + P^T -> per-wave-per-frag LDS
#pragma unroll
        for (int f = 0; f < 2; f++) {
            char* plbf = (char*)Pl + w * 4096 + f * 2048;
#pragma unroll
            for (int nt = 0; nt < 4; nt++) {
                f32x4 sv;
#pragma unroll
                for (int i = 0; i < 4; i++) sv[i] = exp2_(sa[f][nt][i]);
                ls[f] += sv;
                short4v pk;
#pragma unroll
                for (int i = 0; i < 4; i++) pk[i] = f2bf(sv[i]);
                *(short4v*)(plbf + (((lr << 7) + ((nt * 16 + lk * 4) << 1)) ^ ((lr & 7) << 4))) = pk;
            }
        }
        short8 pb[2][2];
#pragma unroll
        for (int f = 0; f < 2; f++) {
            const char* plbf = (const char*)Pl + w * 4096 + f * 2048;
            pb[f][0] = *(const short8*)(plbf + (((lr << 7) + ((lk * 8) << 1)) ^ ((lr & 7) << 4)));
            pb[f][1] = *(const short8*)(plbf + (((lr << 7) + ((32 + lk * 8) << 1)) ^ ((lr & 7) << 4)));
        }
        // O^T += V^T . P ; both frags share each V fragment read
        __builtin_amdgcn_s_setprio(1);
#pragma unroll
        for (int ks = 0; ks < 2; ks++) {
#pragma unroll
            for (int dt = 0; dt < 4; dt++) {
                const short8 vf = lds_frag(VlB, dt * 16 + lr, ks * 64 + lk * 16);
                o[0][dt] = MFMA(vf, pb[0][ks], o[0][dt]);
                o[1][dt] = MFMA(vf, pb[1][ks], o[1][dt]);
            }
        }
        __builtin_amdgcn_s_setprio(0);
    };

    stage(0, 0);  // tile 0 -> buf 0
    for (int it = 0; it < ntile; ++it) {
        const int buf = it & 1;
        __syncthreads();  // drains this tile's gll16 (vmcnt) + syncs
        if (it + 1 < ntile) stage(buf ^ 1, (it + 1) * 64);  // overlaps compute
        const short* KlB = Kl[buf];
        const short* VlB = Vl[buf];
        if (it <= diagA) computeG(qfA, lsA, oA, KlB, VlB, it == diagA);
        if (it <= diagB) computeG(qfB, lsB, oB, KlB, VlB, it == diagB);
    }

    const int b = bh >> 4, h = bh & 15;
#pragma unroll
    for (int f = 0; f < 2; f++) {
        float lA = (lsA[f][0] + lsA[f][1]) + (lsA[f][2] + lsA[f][3]);
        float lB = (lsB[f][0] + lsB[f][1]) + (lsB[f][2] + lsB[f][3]);
        lA += __shfl_xor(lA, 16);
        lA += __shfl_xor(lA, 32);
        lB += __shfl_xor(lB, 16);
        lB += __shfl_xor(lB, 32);
        const float invA = 1.0f / lA, invB = 1.0f / lB;
        short* ypA = Y + ((size_t)b * NT + (qA0 + f * 16 + lr)) * NC + h * ND;
        short* ypB = Y + ((size_t)b * NT + (qB0 + f * 16 + lr)) * NC + h * ND;
#pragma unroll
        for (int dt = 0; dt < 4; dt++) {
            short4v ya, yb2;
#pragma unroll
            for (int i = 0; i < 4; i++) {
                ya[i] = f2bf(oA[f][dt][i] * invA);
                yb2[i] = f2bf(oB[f][dt][i] * invB);
            }
            *(short4v*)(ypA + dt * 16 + lk * 4) = ya;
            *(short4v*)(ypB + dt * 16 + lk * 4) = yb2;
        }
    }
}

extern "C" void kernel_launch(void* const* d_in, const int* in_sizes, int n_in,
                              void* d_out, int out_size, void* d_ws, size_t ws_size,
                              hipStream_t stream) {
    const float* x = (const float*)d_in[0];
    const float* qU = (const float*)d_in[1];
    const float* qV = (const float*)d_in[2];
    const float* kU = (const float*)d_in[3];
    const float* kV = (const float*)d_in[4];
    const float* vU = (const float*)d_in[5];
    const float* vV = (const float*)d_in[6];
    const float* cU = (const float*)d_in[7];
    const float* cV = (const float*)d_in[8];
    float* out = (float*)d_out;

    char* ws = (char*)d_ws;
    size_t off = 0;
    auto take = [&](size_t bytes) {
        char* p = ws + off;
        off += (bytes + 255) & ~(size_t)255;
        return p;
    };
    short* Whi = (short*)take(8 * 65536 * 2);
    short* Wlo = (short*)take(8 * 65536 * 2);
    short* qb = (short*)take((size_t)NM * NC * 2);
    short* kb = (short*)take((size_t)NM * NC * 2);
    short* vtb = (short*)take((size_t)NM * NC * 2);
    short* yb = (short*)take((size_t)NM * NC * 2);

    k_prep<<<256, 256, 0, stream>>>(qV, kV, vV, cV, qU, kU, vU, cU, Whi, Wlo);
    k_qkv<<<256, 512, 0, stream>>>(x, Whi, Wlo, qb, kb, vtb);
    k_attn<<<dim3(8, NB * NH), 256, 0, stream>>>(qb, kb, vtb, yb);
    k_cout<<<256, 512, 0, stream>>>(yb, Whi, Wlo, out);
}